// Round 4
// baseline (185.281 us; speedup 1.0000x reference)
//
#include <hip/hip_runtime.h>
#include <hip/hip_bf16.h>
#include <math.h>

#define B_    2
#define S_    2048
#define HID_  1024
#define H_    16
#define NBQ_  32
#define KSEL_ 8
#define BLK_  64
#define D_    64
#define N3    3072   // q|k|v concatenated columns

typedef __attribute__((ext_vector_type(4))) float f32x4;
typedef __attribute__((ext_vector_type(8))) short short8;
typedef __attribute__((ext_vector_type(8))) unsigned short ushort8;

// f32 -> bf16 bits, round-to-nearest-even (no NaN inputs here)
static __device__ __forceinline__ unsigned short f2bf(float f) {
  unsigned u = __builtin_bit_cast(unsigned, f);
  unsigned r = (u + 0x7FFFu + ((u >> 16) & 1u)) >> 16;
  return (unsigned short)r;
}

static __device__ __forceinline__ void gload_lds16(const void* gptr, void* ldsptr) {
  __builtin_amdgcn_global_load_lds(
      (const __attribute__((address_space(1))) unsigned int*)(uintptr_t)gptr,
      (__attribute__((address_space(3))) unsigned int*)(uintptr_t)ldsptr,
      16, 0, 0);
}

// ---------------- cast hidden (f32 -> bf16), 8 elems/thread ----------------
__global__ __launch_bounds__(256) void cast_hidden_kernel(const float* __restrict__ in,
                                                          unsigned short* __restrict__ ob) {
  int i = blockIdx.x * 256 + threadIdx.x;
  const float4* p = (const float4*)in;
  float4 a = p[2 * i], c = p[2 * i + 1];
  ushort8 o;
  o[0] = f2bf(a.x); o[1] = f2bf(a.y); o[2] = f2bf(a.z); o[3] = f2bf(a.w);
  o[4] = f2bf(c.x); o[5] = f2bf(c.y); o[6] = f2bf(c.z); o[7] = f2bf(c.w);
  *(ushort8*)(ob + (size_t)i * 8) = o;
}

// ---------------- transpose + cast weights: Wt[n][c] = W[c][n] ----------------
__global__ __launch_bounds__(256) void transpose_w_kernel(const float* __restrict__ Wq,
                                                          const float* __restrict__ Wk,
                                                          const float* __restrict__ Wv,
                                                          unsigned short* __restrict__ Wt) {
  __shared__ float tile[32][33];
  const float* W = blockIdx.z == 0 ? Wq : (blockIdx.z == 1 ? Wk : Wv);
  int n0 = blockIdx.x * 32, c0 = blockIdx.y * 32;
  int tx = threadIdx.x & 31, ty = threadIdx.x >> 5;  // 32 x 8
#pragma unroll
  for (int i = 0; i < 32; i += 8) tile[ty + i][tx] = W[(size_t)(c0 + ty + i) * HID_ + n0 + tx];
  __syncthreads();
#pragma unroll
  for (int i = 0; i < 32; i += 8)
    Wt[(size_t)(blockIdx.z * HID_ + n0 + ty + i) * HID_ + c0 + tx] = f2bf(tile[tx][ty + i]);
}

// ---------------- fused QKV GEMM: C[4096][3072] = Ah @ Wt^T + bias ----------------
// A: 4096x1024 bf16 row-major; Bt: 3072x1024 bf16 row-major (N x K); C bf16.
__global__ __launch_bounds__(256) void gemm_qkv_kernel(const unsigned short* __restrict__ A,
                                                       const unsigned short* __restrict__ Bt,
                                                       const float* __restrict__ bq,
                                                       const float* __restrict__ bk,
                                                       const float* __restrict__ bv,
                                                       unsigned short* __restrict__ C) {
  __shared__ alignas(16) unsigned char As[8192];  // 128 rows x 32 k (bf16), 64B/row
  __shared__ alignas(16) unsigned char Bs[8192];
  const int tid = threadIdx.x;
  const int l = tid & 63, w = tid >> 6;
  const int l16 = l & 15, lq = l >> 4;
  const int bm = blockIdx.y * 128, bn = blockIdx.x * 128;
  const int wm = (w >> 1) * 64, wn = (w & 1) * 64;

  f32x4 acc[4][4];
#pragma unroll
  for (int i = 0; i < 4; ++i)
#pragma unroll
    for (int j = 0; j < 4; ++j) { f32x4 z = {0.f, 0.f, 0.f, 0.f}; acc[i][j] = z; }

  // staging: thread t -> row t/4 (and +64), 16B chunk t%4; LDS is linear t*16
  const int srow = tid >> 2, sch = tid & 3;
  const unsigned short* ag = A + (size_t)(bm + srow) * HID_ + sch * 8;
  const unsigned short* bg = Bt + (size_t)(bn + srow) * HID_ + sch * 8;
  unsigned char* asl = As + tid * 16;
  unsigned char* bsl = Bs + tid * 16;

  for (int k0 = 0; k0 < HID_; k0 += 32) {
    __syncthreads();
    gload_lds16(ag + k0, asl);
    gload_lds16(ag + (size_t)64 * HID_ + k0, asl + 4096);
    gload_lds16(bg + k0, bsl);
    gload_lds16(bg + (size_t)64 * HID_ + k0, bsl + 4096);
    __syncthreads();
    short8 af[4], bf[4];
#pragma unroll
    for (int mt = 0; mt < 4; ++mt) af[mt] = *(const short8*)(As + (wm + mt * 16 + l16) * 64 + lq * 16);
#pragma unroll
    for (int nt = 0; nt < 4; ++nt) bf[nt] = *(const short8*)(Bs + (wn + nt * 16 + l16) * 64 + lq * 16);
#pragma unroll
    for (int mt = 0; mt < 4; ++mt)
#pragma unroll
      for (int nt = 0; nt < 4; ++nt)
        acc[mt][nt] = __builtin_amdgcn_mfma_f32_16x16x32_bf16(af[mt], bf[nt], acc[mt][nt], 0, 0, 0);
  }

#pragma unroll
  for (int mt = 0; mt < 4; ++mt) {
#pragma unroll
    for (int nt = 0; nt < 4; ++nt) {
      int col = bn + wn + nt * 16 + l16;
      float bias = col < 1024 ? bq[col] : (col < 2048 ? bk[col - 1024] : bv[col - 2048]);
#pragma unroll
      for (int r = 0; r < 4; ++r) {
        int row = bm + wm + mt * 16 + lq * 4 + r;
        C[(size_t)row * N3 + col] = f2bf(acc[mt][nt][r] + bias);
      }
    }
  }
}

// ---------------- sparse flash attention ----------------
// grid (NBQ, H, B), 256 threads = 4 waves, each wave owns 16 q-rows.
__global__ __launch_bounds__(256) void attn_kernel(const unsigned short* __restrict__ qkv,
                                                   const float* __restrict__ mask,
                                                   const int* __restrict__ kidx,
                                                   float* __restrict__ out) {
  __shared__ alignas(16) unsigned char Kt[8192];     // K block: [key][c], XOR-swizzled
  __shared__ alignas(16) unsigned char Vt[8192];     // V^T block: [d][key], XOR-swizzled
  __shared__ alignas(16) unsigned char Pt[4][2048];  // per-wave P: [qrow][key], swizzled

  const int qb = blockIdx.x, h = blockIdx.y, b = blockIdx.z;
  const int tid = threadIdx.x;
  const int w = tid >> 6, l = tid & 63;
  const int l16 = l & 15, lq = l >> 4;

  // Q fragments in registers (row = l16 within wave's 16-row group, k-chunks 0/1)
  const int qrow_base = qb * 64 + w * 16;
  short8 qf[2];
  {
    const unsigned short* qp = qkv + (size_t)(b * S_ + qrow_base + l16) * N3 + h * 64 + lq * 8;
    qf[0] = *(const short8*)qp;
    qf[1] = *(const short8*)(qp + 32);
  }

  f32x4 Oacc[4];
  float mrow[4], lrow[4];
#pragma unroll
  for (int i = 0; i < 4; ++i) {
    f32x4 z = {0.f, 0.f, 0.f, 0.f};
    Oacc[i] = z; mrow[i] = -__builtin_inff(); lrow[i] = 0.f;
  }

  const int kidx_base = (h * NBQ_ + qb) * KSEL_;
  const int key0 = tid >> 3, ch = tid & 7;  // staging: 32 keys x 8 chunks per half

  for (int it = 0; it < KSEL_; ++it) {
    const int kb = kidx[kidx_base + it];
    __syncthreads();  // prior iter's K/V reads complete before overwrite
#pragma unroll
    for (int half = 0; half < 2; ++half) {
      int key = key0 + half * 32;
      const unsigned short* kp = qkv + (size_t)(b * S_ + kb * 64 + key) * N3 + HID_ + h * 64 + ch * 8;
      short8 kv = *(const short8*)kp;
      *(short8*)(Kt + ((key * 128 + ch * 16) ^ ((key & 7) << 4))) = kv;
      short8 vv = *(const short8*)(kp + HID_);
#pragma unroll
      for (int j = 0; j < 8; ++j) {
        int d = ch * 8 + j;
        *(unsigned short*)(Vt + ((d * 128 + key * 2) ^ ((d & 7) << 4))) = (unsigned short)vv[j];
      }
    }
    __syncthreads();

    // S = Q @ K^T  (D rows = q-rows, cols = keys)
    f32x4 sacc[4];
#pragma unroll
    for (int nt = 0; nt < 4; ++nt) { f32x4 z = {0.f, 0.f, 0.f, 0.f}; sacc[nt] = z; }
#pragma unroll
    for (int kk = 0; kk < 2; ++kk) {
#pragma unroll
      for (int nt = 0; nt < 4; ++nt) {
        int key = nt * 16 + l16;
        short8 kf = *(const short8*)(Kt + ((key * 128 + kk * 64 + lq * 16) ^ ((key & 7) << 4)));
        sacc[nt] = __builtin_amdgcn_mfma_f32_16x16x32_bf16(qf[kk], kf, sacc[nt], 0, 0, 0);
      }
    }

    // scale * multiplicative mask, online softmax over this block's 64 keys
    float sv[4][4];
#pragma unroll
    for (int nt = 0; nt < 4; ++nt)
#pragma unroll
      for (int r = 0; r < 4; ++r) {
        float mval = mask[(size_t)(qb * 64 + w * 16 + lq * 4 + r) * S_ + kb * 64 + nt * 16 + l16];
        sv[nt][r] = sacc[nt][r] * 0.125f * mval;
      }
    float alpha[4];
#pragma unroll
    for (int r = 0; r < 4; ++r) {
      float mx = fmaxf(fmaxf(sv[0][r], sv[1][r]), fmaxf(sv[2][r], sv[3][r]));
#pragma unroll
      for (int off = 1; off < 16; off <<= 1) mx = fmaxf(mx, __shfl_xor(mx, off));
      float mnew = fmaxf(mrow[r], mx);
      alpha[r] = __expf(mrow[r] - mnew);
      float ps = 0.f;
#pragma unroll
      for (int nt = 0; nt < 4; ++nt) { float p = __expf(sv[nt][r] - mnew); sv[nt][r] = p; ps += p; }
#pragma unroll
      for (int off = 1; off < 16; off <<= 1) ps += __shfl_xor(ps, off);
      lrow[r] = lrow[r] * alpha[r] + ps;
      mrow[r] = mnew;
    }
#pragma unroll
    for (int nt = 0; nt < 4; ++nt)
#pragma unroll
      for (int r = 0; r < 4; ++r) Oacc[nt][r] *= alpha[r];

    // write P (bf16) to per-wave swizzled LDS, D-layout -> A-layout transpose
#pragma unroll
    for (int nt = 0; nt < 4; ++nt)
#pragma unroll
      for (int r = 0; r < 4; ++r) {
        int row = lq * 4 + r, col = nt * 16 + l16;
        *(unsigned short*)(Pt[w] + ((row * 128 + col * 2) ^ ((row & 7) << 4))) = f2bf(sv[nt][r]);
      }
    __syncthreads();

    // O += P @ V
#pragma unroll
    for (int kk = 0; kk < 2; ++kk) {
      short8 pf = *(const short8*)(Pt[w] + ((l16 * 128 + kk * 64 + lq * 16) ^ ((l16 & 7) << 4)));
#pragma unroll
      for (int nt = 0; nt < 4; ++nt) {
        int d = nt * 16 + l16;
        short8 vf = *(const short8*)(Vt + ((d * 128 + kk * 64 + lq * 16) ^ ((d & 7) << 4)));
        Oacc[nt] = __builtin_amdgcn_mfma_f32_16x16x32_bf16(pf, vf, Oacc[nt], 0, 0, 0);
      }
    }
  }

  // epilogue: normalize and store f32 out[b][s][h*64+d]
#pragma unroll
  for (int nt = 0; nt < 4; ++nt)
#pragma unroll
    for (int r = 0; r < 4; ++r) {
      int row = qb * 64 + w * 16 + lq * 4 + r;
      out[(size_t)(b * S_ + row) * HID_ + h * 64 + nt * 16 + l16] = Oacc[nt][r] / lrow[r];
    }
}

extern "C" void kernel_launch(void* const* d_in, const int* in_sizes, int n_in,
                              void* d_out, int out_size, void* d_ws, size_t ws_size,
                              hipStream_t stream) {
  const float* hidden = (const float*)d_in[0];
  const float* mask   = (const float*)d_in[1];
  const int*   kidx   = (const int*)d_in[2];
  const float* Wq     = (const float*)d_in[3];
  const float* bq     = (const float*)d_in[4];
  const float* Wk     = (const float*)d_in[5];
  const float* bk     = (const float*)d_in[6];
  const float* Wv     = (const float*)d_in[7];
  const float* bv     = (const float*)d_in[8];
  float* out = (float*)d_out;

  unsigned short* Ah  = (unsigned short*)d_ws;              // 4096x1024 bf16 (8 MB)
  unsigned short* Wt  = Ah + (size_t)4096 * 1024;           // 3072x1024 bf16 (6 MB)
  unsigned short* qkv = Wt + (size_t)3072 * 1024;           // 4096x3072 bf16 (24 MB)

  cast_hidden_kernel<<<2048, 256, 0, stream>>>(hidden, Ah);
  transpose_w_kernel<<<dim3(32, 32, 3), 256, 0, stream>>>(Wq, Wk, Wv, Wt);
  gemm_qkv_kernel<<<dim3(24, 32), 256, 0, stream>>>(Ah, Wt, bq, bk, bv, qkv);
  attn_kernel<<<dim3(32, 16, 2), 256, 0, stream>>>(qkv, mask, kidx, out);
}

// Round 10
// 174.660 us; speedup vs baseline: 1.0608x; 1.0608x over previous
//
#include <hip/hip_runtime.h>
#include <hip/hip_bf16.h>
#include <math.h>

#define B_    2
#define S_    2048
#define HID_  1024
#define H_    16
#define NBQ_  32
#define KSEL_ 8
#define BLK_  64
#define D_    64
#define N3    3072   // q|k|v concatenated columns

typedef __attribute__((ext_vector_type(4))) float f32x4;
typedef __attribute__((ext_vector_type(8))) short short8;
typedef __attribute__((ext_vector_type(8))) unsigned short ushort8;
typedef __attribute__((ext_vector_type(2))) unsigned int uint2v;
typedef __attribute__((ext_vector_type(4))) unsigned int uint4v;

// f32 -> bf16 bits, round-to-nearest-even (no NaN inputs here)
static __device__ __forceinline__ unsigned short f2bf(float f) {
  unsigned u = __builtin_bit_cast(unsigned, f);
  unsigned r = (u + 0x7FFFu + ((u >> 16) & 1u)) >> 16;
  return (unsigned short)r;
}

static __device__ __forceinline__ void gload_lds16(const void* gptr, void* ldsptr) {
  __builtin_amdgcn_global_load_lds(
      (const __attribute__((address_space(1))) unsigned int*)(uintptr_t)gptr,
      (__attribute__((address_space(3))) unsigned int*)(uintptr_t)ldsptr,
      16, 0, 0);
}

// ---------------- cast hidden (f32 -> bf16), 8 elems/thread ----------------
__global__ __launch_bounds__(256) void cast_hidden_kernel(const float* __restrict__ in,
                                                          unsigned short* __restrict__ ob) {
  int i = blockIdx.x * 256 + threadIdx.x;
  const float4* p = (const float4*)in;
  float4 a = p[2 * i], c = p[2 * i + 1];
  ushort8 o;
  o[0] = f2bf(a.x); o[1] = f2bf(a.y); o[2] = f2bf(a.z); o[3] = f2bf(a.w);
  o[4] = f2bf(c.x); o[5] = f2bf(c.y); o[6] = f2bf(c.z); o[7] = f2bf(c.w);
  *(ushort8*)(ob + (size_t)i * 8) = o;
}

// ---------------- transpose + cast weights: Wt[n][c] = W[c][n] ----------------
__global__ __launch_bounds__(256) void transpose_w_kernel(const float* __restrict__ Wq,
                                                          const float* __restrict__ Wk,
                                                          const float* __restrict__ Wv,
                                                          unsigned short* __restrict__ Wt) {
  __shared__ float tile[32][33];
  const float* W = blockIdx.z == 0 ? Wq : (blockIdx.z == 1 ? Wk : Wv);
  int n0 = blockIdx.x * 32, c0 = blockIdx.y * 32;
  int tx = threadIdx.x & 31, ty = threadIdx.x >> 5;  // 32 x 8
#pragma unroll
  for (int i = 0; i < 32; i += 8) tile[ty + i][tx] = W[(size_t)(c0 + ty + i) * HID_ + n0 + tx];
  __syncthreads();
#pragma unroll
  for (int i = 0; i < 32; i += 8)
    Wt[(size_t)(blockIdx.z * HID_ + n0 + ty + i) * HID_ + c0 + tx] = f2bf(tile[tx][ty + i]);
}

// ---------------- fused QKV GEMM: C[4096][3072] = Ah @ Wt^T + bias ----------------
__global__ __launch_bounds__(256) void gemm_qkv_kernel(const unsigned short* __restrict__ A,
                                                       const unsigned short* __restrict__ Bt,
                                                       const float* __restrict__ bq,
                                                       const float* __restrict__ bk,
                                                       const float* __restrict__ bv,
                                                       unsigned short* __restrict__ C) {
  __shared__ alignas(16) unsigned char As[8192];  // 128 rows x 32 k (bf16), 64B/row
  __shared__ alignas(16) unsigned char Bs[8192];
  const int tid = threadIdx.x;
  const int l = tid & 63, w = tid >> 6;
  const int l16 = l & 15, lq = l >> 4;
  const int bm = blockIdx.y * 128, bn = blockIdx.x * 128;
  const int wm = (w >> 1) * 64, wn = (w & 1) * 64;

  f32x4 acc[4][4];
#pragma unroll
  for (int i = 0; i < 4; ++i)
#pragma unroll
    for (int j = 0; j < 4; ++j) { f32x4 z = {0.f, 0.f, 0.f, 0.f}; acc[i][j] = z; }

  const int srow = tid >> 2, sch = tid & 3;
  const unsigned short* ag = A + (size_t)(bm + srow) * HID_ + sch * 8;
  const unsigned short* bg = Bt + (size_t)(bn + srow) * HID_ + sch * 8;
  unsigned char* asl = As + tid * 16;
  unsigned char* bsl = Bs + tid * 16;

  for (int k0 = 0; k0 < HID_; k0 += 32) {
    __syncthreads();
    gload_lds16(ag + k0, asl);
    gload_lds16(ag + (size_t)64 * HID_ + k0, asl + 4096);
    gload_lds16(bg + k0, bsl);
    gload_lds16(bg + (size_t)64 * HID_ + k0, bsl + 4096);
    __syncthreads();
    short8 af[4], bf[4];
#pragma unroll
    for (int mt = 0; mt < 4; ++mt) af[mt] = *(const short8*)(As + (wm + mt * 16 + l16) * 64 + lq * 16);
#pragma unroll
    for (int nt = 0; nt < 4; ++nt) bf[nt] = *(const short8*)(Bs + (wn + nt * 16 + l16) * 64 + lq * 16);
#pragma unroll
    for (int mt = 0; mt < 4; ++mt)
#pragma unroll
      for (int nt = 0; nt < 4; ++nt)
        acc[mt][nt] = __builtin_amdgcn_mfma_f32_16x16x32_bf16(af[mt], bf[nt], acc[mt][nt], 0, 0, 0);
  }

#pragma unroll
  for (int mt = 0; mt < 4; ++mt) {
#pragma unroll
    for (int nt = 0; nt < 4; ++nt) {
      int col = bn + wn + nt * 16 + l16;
      float bias = col < 1024 ? bq[col] : (col < 2048 ? bk[col - 1024] : bv[col - 2048]);
#pragma unroll
      for (int r = 0; r < 4; ++r) {
        int row = bm + wm + mt * 16 + lq * 4 + r;
        C[(size_t)row * N3 + col] = f2bf(acc[mt][nt][r] + bias);
      }
    }
  }
}

// ---------------- sparse flash attention ----------------
// grid (NBQ, H, B), 256 threads = 4 waves, each wave owns 16 q-rows.
// K LDS: [key][c] rows of 128B, XOR-swizzled (read: lanes = 16 rows, same chunk).
// V LDS: subtiled [key/4][d/16][4][16] bf16, 128B/subtile (subtile idx = kq*4+dq);
//        staged with linear 16B writes (conflict-free).
// PV B-frags via ds_read_b64_tr_b16: the 16-lane group must cover the 128B
//        subtile with per-lane addr = sub + 8*(lane&15) B (m156-verified wiring
//        O[4a+b][j] = I[a+4j][b]); lane l16 then receives column l16, rows j=0..3.
//        keys j=0..3 at subtile kq, j=4..7 at kq+1 = +512B.
__global__ __launch_bounds__(256) void attn_kernel(const unsigned short* __restrict__ qkv,
                                                   const float* __restrict__ mask,
                                                   const int* __restrict__ kidx,
                                                   float* __restrict__ out) {
  __shared__ alignas(16) unsigned char Kt[8192];
  __shared__ alignas(16) unsigned char Vs[8192];
  __shared__ alignas(16) unsigned char Pt[4][2048];  // per-wave P: [qrow][key], swizzled

  const int qb = blockIdx.x, h = blockIdx.y, b = blockIdx.z;
  const int tid = threadIdx.x;
  const int w = tid >> 6, l = tid & 63;
  const int l16 = l & 15, lq = l >> 4;

  const int qrow_base = qb * 64 + w * 16;
  short8 qf[2];
  {
    const unsigned short* qp = qkv + (size_t)(b * S_ + qrow_base + l16) * N3 + h * 64 + lq * 8;
    qf[0] = *(const short8*)qp;
    qf[1] = *(const short8*)(qp + 32);
  }

  f32x4 Oacc[4];
  float mrow[4], lrow[4];
#pragma unroll
  for (int i = 0; i < 4; ++i) {
    f32x4 z = {0.f, 0.f, 0.f, 0.f};
    Oacc[i] = z; mrow[i] = -__builtin_inff(); lrow[i] = 0.f;
  }

  const int kidx_base = (h * NBQ_ + qb) * KSEL_;
  const int key0 = tid >> 3, ch = tid & 7;  // staging: 32 keys x 8 chunks per half
  const int qrow0 = qrow_base + lq * 4;     // mask row base for this lane

  // ---- prologue: prefetch iter-0 K/V into registers (T14) ----
  int kb = kidx[kidx_base];
  short8 kreg[2], vreg[2];
  {
    const unsigned short* kp0 = qkv + (size_t)(b * S_ + kb * 64 + key0) * N3 + HID_ + h * 64 + ch * 8;
    kreg[0] = *(const short8*)kp0;
    vreg[0] = *(const short8*)(kp0 + HID_);
    const unsigned short* kp1 = kp0 + (size_t)32 * N3;
    kreg[1] = *(const short8*)kp1;
    vreg[1] = *(const short8*)(kp1 + HID_);
  }

  for (int it = 0; it < KSEL_; ++it) {
    __syncthreads();  // all waves done reading prev iter's Kt/Vs
    // ---- stage K/V from regs (conflict-free 16B writes) ----
#pragma unroll
    for (int half = 0; half < 2; ++half) {
      int key = key0 + half * 32;
      *(short8*)(Kt + ((key * 128 + ch * 16) ^ ((key & 7) << 4))) = kreg[half];
      *(short8*)(Vs + ((key >> 2) * 512 + (ch >> 1) * 128 + (key & 3) * 32 + (ch & 1) * 16)) = vreg[half];
    }
    __syncthreads();

    // ---- issue mask loads (current kb) + next-iter K/V prefetch ----
    float mv[4][4];
#pragma unroll
    for (int nt = 0; nt < 4; ++nt)
#pragma unroll
      for (int r = 0; r < 4; ++r)
        mv[nt][r] = mask[(size_t)(qrow0 + r) * S_ + kb * 64 + nt * 16 + l16];

    if (it + 1 < KSEL_) {
      kb = kidx[kidx_base + it + 1];
      const unsigned short* kp0 = qkv + (size_t)(b * S_ + kb * 64 + key0) * N3 + HID_ + h * 64 + ch * 8;
      kreg[0] = *(const short8*)kp0;
      vreg[0] = *(const short8*)(kp0 + HID_);
      const unsigned short* kp1 = kp0 + (size_t)32 * N3;
      kreg[1] = *(const short8*)kp1;
      vreg[1] = *(const short8*)(kp1 + HID_);
    }

    // ---- S = Q @ K^T ----
    f32x4 sacc[4];
#pragma unroll
    for (int nt = 0; nt < 4; ++nt) { f32x4 z = {0.f, 0.f, 0.f, 0.f}; sacc[nt] = z; }
#pragma unroll
    for (int kk = 0; kk < 2; ++kk) {
#pragma unroll
      for (int nt = 0; nt < 4; ++nt) {
        int key = nt * 16 + l16;
        short8 kf = *(const short8*)(Kt + ((key * 128 + kk * 64 + lq * 16) ^ ((key & 7) << 4)));
        sacc[nt] = __builtin_amdgcn_mfma_f32_16x16x32_bf16(qf[kk], kf, sacc[nt], 0, 0, 0);
      }
    }

    // ---- scale * mask, online softmax over 64 keys ----
    float sv[4][4];
#pragma unroll
    for (int nt = 0; nt < 4; ++nt)
#pragma unroll
      for (int r = 0; r < 4; ++r)
        sv[nt][r] = sacc[nt][r] * 0.125f * mv[nt][r];
    float alpha[4];
#pragma unroll
    for (int r = 0; r < 4; ++r) {
      float mx = fmaxf(fmaxf(sv[0][r], sv[1][r]), fmaxf(sv[2][r], sv[3][r]));
#pragma unroll
      for (int off = 1; off < 16; off <<= 1) mx = fmaxf(mx, __shfl_xor(mx, off));
      float mnew = fmaxf(mrow[r], mx);
      alpha[r] = __expf(mrow[r] - mnew);
      float ps = 0.f;
#pragma unroll
      for (int nt = 0; nt < 4; ++nt) { float p = __expf(sv[nt][r] - mnew); sv[nt][r] = p; ps += p; }
#pragma unroll
      for (int off = 1; off < 16; off <<= 1) ps += __shfl_xor(ps, off);
      lrow[r] = lrow[r] * alpha[r] + ps;
      mrow[r] = mnew;
    }
#pragma unroll
    for (int nt = 0; nt < 4; ++nt)
#pragma unroll
      for (int r = 0; r < 4; ++r) Oacc[nt][r] *= alpha[r];

    // ---- P (bf16) -> per-wave swizzled LDS (D-layout -> A-layout transpose) ----
#pragma unroll
    for (int nt = 0; nt < 4; ++nt)
#pragma unroll
      for (int r = 0; r < 4; ++r) {
        int row = lq * 4 + r, col = nt * 16 + l16;
        *(unsigned short*)(Pt[w] + ((row * 128 + col * 2) ^ ((row & 7) << 4))) = f2bf(sv[nt][r]);
      }
    // no __syncthreads: Pt is wave-local; lgkmcnt ordering suffices

    // ---- O += P @ V  (V B-frags via hardware transpose read) ----
#pragma unroll
    for (int kk = 0; kk < 2; ++kk) {
      short8 pf = *(const short8*)(Pt[w] + ((l16 * 128 + kk * 64 + lq * 16) ^ ((l16 & 7) << 4)));
      uint2v t[4][2];
#pragma unroll
      for (int nt = 0; nt < 4; ++nt) {
        // subtile (kq=kk*8+lq*2, dq=nt); group covers 128B: addr = sub + 8*l16
        unsigned int base = (unsigned int)(uintptr_t)(Vs + ((kk * 8 + lq * 2) * 4 + nt) * 128 + l16 * 8);
        asm volatile("ds_read_b64_tr_b16 %0, %1" : "=v"(t[nt][0]) : "v"(base) : "memory");
        asm volatile("ds_read_b64_tr_b16 %0, %1" : "=v"(t[nt][1]) : "v"(base + 512u) : "memory");
      }
      asm volatile("s_waitcnt lgkmcnt(0)" ::: "memory");
      __builtin_amdgcn_sched_barrier(0);
#pragma unroll
      for (int nt = 0; nt < 4; ++nt) {
        uint4v u = {t[nt][0][0], t[nt][0][1], t[nt][1][0], t[nt][1][1]};
        short8 vf = __builtin_bit_cast(short8, u);
        Oacc[nt] = __builtin_amdgcn_mfma_f32_16x16x32_bf16(pf, vf, Oacc[nt], 0, 0, 0);
      }
    }
  }

  // ---- epilogue: normalize and store f32 out[b][s][h*64+d] ----
#pragma unroll
  for (int nt = 0; nt < 4; ++nt)
#pragma unroll
    for (int r = 0; r < 4; ++r) {
      int row = qb * 64 + w * 16 + lq * 4 + r;
      out[(size_t)(b * S_ + row) * HID_ + h * 64 + nt * 16 + l16] = Oacc[nt][r] / lrow[r];
    }
}

extern "C" void kernel_launch(void* const* d_in, const int* in_sizes, int n_in,
                              void* d_out, int out_size, void* d_ws, size_t ws_size,
                              hipStream_t stream) {
  const float* hidden = (const float*)d_in[0];
  const float* mask   = (const float*)d_in[1];
  const int*   kidx   = (const int*)d_in[2];
  const float* Wq     = (const float*)d_in[3];
  const float* bq     = (const float*)d_in[4];
  const float* Wk     = (const float*)d_in[5];
  const float* bk     = (const float*)d_in[6];
  const float* Wv     = (const float*)d_in[7];
  const float* bv     = (const float*)d_in[8];
  float* out = (float*)d_out;

  unsigned short* Ah  = (unsigned short*)d_ws;              // 4096x1024 bf16 (8 MB)
  unsigned short* Wt  = Ah + (size_t)4096 * 1024;           // 3072x1024 bf16 (6 MB)
  unsigned short* qkv = Wt + (size_t)3072 * 1024;           // 4096x3072 bf16 (24 MB)

  cast_hidden_kernel<<<2048, 256, 0, stream>>>(hidden, Ah);
  transpose_w_kernel<<<dim3(32, 32, 3), 256, 0, stream>>>(Wq, Wk, Wv, Wt);
  gemm_qkv_kernel<<<dim3(24, 32), 256, 0, stream>>>(Ah, Wt, bq, bk, bv, qkv);
  attn_kernel<<<dim3(32, 16, 2), 256, 0, stream>>>(qkv, mask, kidx, out);
}